// Round 9
// baseline (195.103 us; speedup 1.0000x reference)
//
#include <hip/hip_runtime.h>

// Linear attention (non-causal), N=4, L=8192, H=16, D=M=64, fp32.
//   fm(x) = elu(x)+1
//   KV[n,h,d,m] = sum_s fm(K[n,s,h,d]) * V[n,s,h,m]
//   Ksum[n,h,d] = sum_s fm(K[n,s,h,d])
//   z[n,l,h]    = 1/(fm(Q[n,l,h,:]) . Ksum[n,h,:]) + 1e-10
//   out[n,l,h,m]= z * sum_d fm(Q[n,l,h,d]) * KV[d][m]
//
// R8 post-mortem: spill fixed (FETCH ideal, VGPR 100) but per-row serial
// [4 ds_read -> lgkm -> 64 FMA] exposes ~120cyc LDS latency 8x/tile ->
// VALU 27%. R9: ping-pong fragment regs (read r+1 before FMA(r)) + 4-row
// tiles (prefetch 16->8 regs, ks 8->4) => ~123 VGPR fits the (256,2)=128
// cap. Layout [octet][row] stride-36, conflict-free. Combine buf aliased.

#define EPSV      1e-10f
#define L_SEQ     8192
#define NH_TOT    64
#define ROWSTRIDE 1024
#define KV_STRIDE 4160
#define SLICE     (NH_TOT * KV_STRIDE)   // 266240 floats per chunk-slice
#define CH_SPLIT  32
#define QSTRIDE   68
#define WSTR      36                     // LDS octet stride (4 rows * 8 + pad 4)
#define WWIN      (8 * WSTR)             // one window: 288 floats
#define WAVEWIN   (2 * WWIN)             // K+V windows per wave: 576 floats

__device__ __forceinline__ float fm(float x) {
    return x > 0.0f ? x + 1.0f : __expf(x);
}

// ==================== Pass 1: KV + Ksum partials ====================
// grid (64 nh, 32 chunk), block 256 = 4 waves; wave w owns s-rows
// [chunk*256 + w*64, +64) as 16 tiles of 4 rows.
// Lane patch: d0=(lane>>3)*8, m0=(lane&7)*8, acc[8][8] (64 VGPR).
// Staging: lane loads row (lane>>4), cols (lane&15)*4 (256B/16-lane coalesced).
// LDS window [octet g][row r][8] floats, octet stride 36: writes hit 8
// distinct 4-bank clusters (min phases); reads are 8-lane broadcasts across
// 8 clusters (conflict-free).
__global__ __launch_bounds__(256, 2) void kv_pass_kernel(
    const float* __restrict__ K, const float* __restrict__ V,
    float* __restrict__ ws, int mode)
{
    const int t     = threadIdx.x;
    const int nh    = blockIdx.x;
    const int chunk = blockIdx.y;
    const int n = nh >> 4, h = nh & 15;
    const int wid  = t >> 6;
    const int lane = t & 63;

    const int d0 = (lane >> 3) << 3;   // patch rows (d)
    const int m0 = (lane & 7) << 3;    // patch cols (m)

    const int srow = lane >> 4;        // staging row 0..3
    const int q4   = lane & 15;        // staging col-quad 0..15
    const int g    = q4 >> 1;          // octet
    const int h2   = q4 & 1;           // half of octet

    __shared__ float smem[4096];       // 16KB: wave windows, then combine buf
    __shared__ float ksw[4][64];       // 1KB: per-wave ksum

    float* kws = &smem[wid * WAVEWIN];
    float* vws = kws + WWIN;

    float acc[8][8] = {};
    float ks[4] = {};

    const size_t nbase = (size_t)n * (L_SEQ * ROWSTRIDE) + h * 64;
    const int r0 = chunk * 256 + wid * 64;          // wave's first s-row
    const float* Kst = K + nbase + (size_t)(r0 + srow) * ROWSTRIDE + q4 * 4;
    const float* Vst = V + nbase + (size_t)(r0 + srow) * ROWSTRIDE + q4 * 4;

    const int wofs = g * WSTR + srow * 8 + h2 * 4;  // write offset
    const int krd  = (lane >> 3) * WSTR;            // K read base (d-octet)
    const int vrd  = (lane & 7) * WSTR;             // V read base (m-octet)

    // prologue: prefetch tile 0 (1 b128 K + 1 b128 V per lane)
    float4 kr = *reinterpret_cast<const float4*>(Kst);
    float4 vr = *reinterpret_cast<const float4*>(Vst);

#define RD_FRAG(KA, KB, VA, VB, R)                                          \
    KA = *reinterpret_cast<const float4*>(&kws[krd + (R) * 8]);             \
    KB = *reinterpret_cast<const float4*>(&kws[krd + (R) * 8 + 4]);         \
    VA = *reinterpret_cast<const float4*>(&vws[vrd + (R) * 8]);             \
    VB = *reinterpret_cast<const float4*>(&vws[vrd + (R) * 8 + 4]);

#define ACC8(AI, KC, VA, VB)                                                \
    acc[AI][0] += (KC) * (VA).x; acc[AI][1] += (KC) * (VA).y;               \
    acc[AI][2] += (KC) * (VA).z; acc[AI][3] += (KC) * (VA).w;               \
    acc[AI][4] += (KC) * (VB).x; acc[AI][5] += (KC) * (VB).y;               \
    acc[AI][6] += (KC) * (VB).z; acc[AI][7] += (KC) * (VB).w;

#define FMA_FRAG(KA, KB, VA, VB)                                            \
    ACC8(0, (KA).x, VA, VB) ACC8(1, (KA).y, VA, VB)                         \
    ACC8(2, (KA).z, VA, VB) ACC8(3, (KA).w, VA, VB)                         \
    ACC8(4, (KB).x, VA, VB) ACC8(5, (KB).y, VA, VB)                         \
    ACC8(6, (KB).z, VA, VB) ACC8(7, (KB).w, VA, VB)

#pragma unroll 1
    for (int tile = 0; tile < 16; ++tile) {
        // fm + ksum + stage current 4-row tile
        float4 kf;
        kf.x = fm(kr.x); kf.y = fm(kr.y); kf.z = fm(kr.z); kf.w = fm(kr.w);
        ks[0] += kf.x; ks[1] += kf.y; ks[2] += kf.z; ks[3] += kf.w;
        *reinterpret_cast<float4*>(&kws[wofs]) = kf;
        *reinterpret_cast<float4*>(&vws[wofs]) = vr;

        // prefetch next tile (flies under the 256 FMA-instr below)
        if (tile < 15) {
            const float* kp = Kst + (size_t)(tile + 1) * (4 * ROWSTRIDE);
            const float* vp = Vst + (size_t)(tile + 1) * (4 * ROWSTRIDE);
            kr = *reinterpret_cast<const float4*>(kp);
            vr = *reinterpret_cast<const float4*>(vp);
        }

        // ping-pong pipelined fragment reads: read r+1 before FMA(r)
        float4 kaA, kbA, vaA, vbA, kaB, kbB, vaB, vbB;
        RD_FRAG(kaA, kbA, vaA, vbA, 0)
        RD_FRAG(kaB, kbB, vaB, vbB, 1)
        FMA_FRAG(kaA, kbA, vaA, vbA)            // r=0
        RD_FRAG(kaA, kbA, vaA, vbA, 2)
        FMA_FRAG(kaB, kbB, vaB, vbB)            // r=1
        RD_FRAG(kaB, kbB, vaB, vbB, 3)
        FMA_FRAG(kaA, kbA, vaA, vbA)            // r=2
        FMA_FRAG(kaB, kbB, vaB, vbB)            // r=3
    }

#undef RD_FRAG
#undef ACC8
#undef FMA_FRAG

    // ksum: lanes {l, l^16, l^32, l^48} share col-quad q4
#pragma unroll
    for (int j = 0; j < 4; ++j) {
        ks[j] += __shfl_xor(ks[j], 16);
        ks[j] += __shfl_xor(ks[j], 32);
    }
    if (lane < 16) {
        *reinterpret_cast<float4*>(&ksw[wid][lane * 4]) =
            make_float4(ks[0], ks[1], ks[2], ks[3]);
    }

    // all waves done with windows before aliasing them as combine buffer
    __syncthreads();
    float* red = smem;

    // cross-wave KV combine (sequential, 4 barriers)
    for (int w = 0; w < 4; ++w) {
        if (wid == w) {
#pragma unroll
            for (int i = 0; i < 8; ++i) {
                float* p = &red[(d0 + i) * 64 + m0];
                float4 a0 = make_float4(acc[i][0], acc[i][1], acc[i][2], acc[i][3]);
                float4 a1 = make_float4(acc[i][4], acc[i][5], acc[i][6], acc[i][7]);
                if (w != 0) {
                    const float4 b0 = *reinterpret_cast<const float4*>(p);
                    const float4 b1 = *reinterpret_cast<const float4*>(p + 4);
                    a0.x += b0.x; a0.y += b0.y; a0.z += b0.z; a0.w += b0.w;
                    a1.x += b1.x; a1.y += b1.y; a1.z += b1.z; a1.w += b1.w;
                }
                *reinterpret_cast<float4*>(p)     = a0;
                *reinterpret_cast<float4*>(p + 4) = a1;
            }
        }
        __syncthreads();
    }

    float* dst = ws + (size_t)(mode ? (chunk * NH_TOT + nh) : nh) * KV_STRIDE;
    if (mode) {
#pragma unroll
        for (int i = 0; i < 4; ++i)
            *reinterpret_cast<float4*>(dst + t * 16 + i * 4) =
                *reinterpret_cast<const float4*>(&red[t * 16 + i * 4]);
        if (t < 64)
            dst[4096 + t] = ksw[0][t] + ksw[1][t] + ksw[2][t] + ksw[3][t];
    } else {
#pragma unroll
        for (int i = 0; i < 16; ++i)
            atomicAdd(dst + t * 16 + i, red[t * 16 + i]);
        if (t < 64)
            atomicAdd(dst + 4096 + t, ksw[0][t] + ksw[1][t] + ksw[2][t] + ksw[3][t]);
    }
}

// ==================== Reduce: sum CH slices into slice 0 ====================
__global__ __launch_bounds__(256) void reduce_kernel(float* __restrict__ ws, int CH)
{
    const int idx = blockIdx.x * 256 + threadIdx.x;
    float s = 0.f;
    for (int c = 0; c < CH; ++c) s += ws[(size_t)c * SLICE + idx];
    ws[idx] = s;
}

// ==================== Pass 2: out = z * (fm(Q) @ KV) ====================
// R2-verbatim (proven). grid (128, 64 nh), block 256.
__global__ __launch_bounds__(256) void out_kernel(
    const float* __restrict__ Q, const float* __restrict__ KVg,
    float* __restrict__ out)
{
    const int t      = threadIdx.x;
    const int lchunk = blockIdx.x;
    const int nh     = blockIdx.y;
    const int n = nh >> 4, h = nh & 15;

    __shared__ float Ql[64 * QSTRIDE];
    __shared__ float KVl[4096];
    __shared__ float Ks[64];
    __shared__ float zl[64];

    const float* kvrow = KVg + (size_t)nh * KV_STRIDE;

#pragma unroll
    for (int j = 0; j < 4; ++j) {
        reinterpret_cast<float4*>(KVl)[t + 256 * j] =
            reinterpret_cast<const float4*>(kvrow)[t + 256 * j];
    }
    if (t < 16) {
        reinterpret_cast<float4*>(Ks)[t] =
            reinterpret_cast<const float4*>(kvrow + 4096)[t];
    }
    __syncthreads();

    const int lane16 = t & 15, grp = t >> 4;
    const int dq = lane16 << 2;
    const float4 ks4 = *reinterpret_cast<const float4*>(&Ks[dq]);
    const size_t qbase = ((size_t)n * L_SEQ + lchunk * 64) * ROWSTRIDE + h * 64;
#pragma unroll
    for (int p = 0; p < 4; ++p) {
        const int rr = p * 16 + grp;
        const float4 qg = *reinterpret_cast<const float4*>(Q + qbase + (size_t)rr * ROWSTRIDE + dq);
        float4 qf;
        qf.x = fm(qg.x); qf.y = fm(qg.y); qf.z = fm(qg.z); qf.w = fm(qg.w);
        *reinterpret_cast<float4*>(&Ql[rr * QSTRIDE + dq]) = qf;
        float dp = qf.x * ks4.x + qf.y * ks4.y + qf.z * ks4.z + qf.w * ks4.w;
        dp += __shfl_xor(dp, 1);
        dp += __shfl_xor(dp, 2);
        dp += __shfl_xor(dp, 4);
        dp += __shfl_xor(dp, 8);
        if (lane16 == 0) zl[rr] = 1.0f / dp + EPSV;
    }
    __syncthreads();

    const int r0 = grp << 2;
    const int c0 = lane16 << 2;
    float acc[4][4] = {};
#pragma unroll 2
    for (int d = 0; d < 64; d += 4) {
        const float4 b0 = *reinterpret_cast<const float4*>(&KVl[(d + 0) * 64 + c0]);
        const float4 b1 = *reinterpret_cast<const float4*>(&KVl[(d + 1) * 64 + c0]);
        const float4 b2 = *reinterpret_cast<const float4*>(&KVl[(d + 2) * 64 + c0]);
        const float4 b3 = *reinterpret_cast<const float4*>(&KVl[(d + 3) * 64 + c0]);
#define DO_ROW(i) do {                                                              \
        const float4 q = *reinterpret_cast<const float4*>(&Ql[(r0 + (i)) * QSTRIDE + d]); \
        acc[i][0] += q.x * b0.x + q.y * b1.x + q.z * b2.x + q.w * b3.x;             \
        acc[i][1] += q.x * b0.y + q.y * b1.y + q.z * b2.y + q.w * b3.y;             \
        acc[i][2] += q.x * b0.z + q.y * b1.z + q.z * b2.z + q.w * b3.z;             \
        acc[i][3] += q.x * b0.w + q.y * b1.w + q.z * b2.w + q.w * b3.w;             \
    } while (0)
        DO_ROW(0); DO_ROW(1); DO_ROW(2); DO_ROW(3);
#undef DO_ROW
    }

#pragma unroll
    for (int i = 0; i < 4; ++i) {
        const float z = zl[r0 + i];
        float4 o;
        o.x = acc[i][0] * z; o.y = acc[i][1] * z; o.z = acc[i][2] * z; o.w = acc[i][3] * z;
        *reinterpret_cast<float4*>(out + qbase + (size_t)(r0 + i) * ROWSTRIDE + c0) = o;
    }
}

extern "C" void kernel_launch(void* const* d_in, const int* in_sizes, int n_in,
                              void* d_out, int out_size, void* d_ws, size_t ws_size,
                              hipStream_t stream) {
    const float* Q = (const float*)d_in[0];
    const float* K = (const float*)d_in[1];
    const float* V = (const float*)d_in[2];
    float* out = (float*)d_out;
    float* ws  = (float*)d_ws;

    const size_t per_slice = (size_t)SLICE * sizeof(float);   // ~1.06 MB
    const bool split = ws_size >= per_slice * CH_SPLIT;

    if (split) {
        kv_pass_kernel<<<dim3(NH_TOT, CH_SPLIT), 256, 0, stream>>>(K, V, ws, 1);
        reduce_kernel<<<SLICE / 256, 256, 0, stream>>>(ws, CH_SPLIT);
    } else {
        hipMemsetAsync(ws, 0, per_slice, stream);
        kv_pass_kernel<<<dim3(NH_TOT, CH_SPLIT), 256, 0, stream>>>(K, V, ws, 0);
    }
    out_kernel<<<dim3(L_SEQ / 64, NH_TOT), 256, 0, stream>>>(Q, ws, out);
}